// Round 1
// baseline (395.041 us; speedup 1.0000x reference)
//
#include <hip/hip_runtime.h>

typedef float  f32x4  __attribute__((ext_vector_type(4)));
typedef __bf16 bf16x8 __attribute__((ext_vector_type(8)));
typedef unsigned short u16;
typedef u16 u16x8 __attribute__((ext_vector_type(8)));
typedef u16 u16x4 __attribute__((ext_vector_type(4)));

#define HEADS 16
#define DIM   128
#define QT    64
#define KTILE 64
#define KSTR  136   // 128 + 8 pad (keeps 16B alignment, 2-way-free banks)
#define VSTR  72    // 64 + 8 pad
#define PSTR  72

__device__ __forceinline__ u16 f2bf(float f) {
    unsigned u = __builtin_bit_cast(unsigned, f);
    u += 0x7FFFu + ((u >> 16) & 1u);   // RNE
    return (u16)(u >> 16);
}

__global__ __launch_bounds__(256, 2) void fa_blockcausal(
    const float* __restrict__ Q, const float* __restrict__ K,
    const float* __restrict__ V, const void* __restrict__ cu_raw,
    int n_cu, float* __restrict__ O, int S)
{
    __shared__ __align__(16) u16 Kb[KTILE * KSTR];   // K tile, row-major bf16
    __shared__ __align__(16) u16 Vt[DIM * VSTR];     // V tile, transposed bf16
    __shared__ __align__(16) u16 Pw[4][16 * PSTR];   // per-wave P staging
    __shared__ int cu_s[32];

    const int tid  = threadIdx.x;
    const int wave = tid >> 6, lane = tid & 63;
    const int quad = lane >> 4, l16 = lane & 15;
    const int q0   = blockIdx.x * QT;
    const int h    = blockIdx.y;

    // cu_seqlens: runtime int64/int32 sniff (inner boundaries are >=1, so
    // word[1]==0 iff storage is int64 little-endian)
    {
        const int* cu32 = (const int*)cu_raw;
        bool is64 = (cu32[1] == 0);
        for (int t = tid; t < n_cu; t += blockDim.x)
            cu_s[t] = is64 ? (int)((const long long*)cu_raw)[t] : cu32[t];
    }
    __syncthreads();

    const long hb = (long)h * S * DIM;
    const float NEG_INF = -__builtin_inff();
    const float scale = 0.08838834764831845f;   // 1/sqrt(128)

    // per-row query index + doc start (mask: doc_start(qi) <= kj <= qi)
    int qrow[4], qstart[4];
#pragma unroll
    for (int r = 0; r < 4; ++r) {
        int qi = q0 + wave * 16 + quad * 4 + r;
        qrow[r] = qi;
        int st = 0;
        for (int j = 0; j < n_cu; ++j) if (cu_s[j] <= qi) st = cu_s[j];
        qstart[r] = st;
    }
    int q0s = 0;
    for (int j = 0; j < n_cu; ++j) if (cu_s[j] <= q0) q0s = cu_s[j];
    const int kt0 = q0s & ~(KTILE - 1);

    // Q fragments (A-layout: A[m=l16][k=quad*8+j], per 32-wide k-step)
    bf16x8 qfrag[4];
    {
        const int row = q0 + wave * 16 + l16;
        const float* qp = Q + hb + (long)row * DIM + quad * 8;
#pragma unroll
        for (int kk = 0; kk < 4; ++kk) {
            f32x4 x = *(const f32x4*)(qp + kk * 32);
            f32x4 y = *(const f32x4*)(qp + kk * 32 + 4);
            u16x8 u;
            u[0]=f2bf(x[0]); u[1]=f2bf(x[1]); u[2]=f2bf(x[2]); u[3]=f2bf(x[3]);
            u[4]=f2bf(y[0]); u[5]=f2bf(y[1]); u[6]=f2bf(y[2]); u[7]=f2bf(y[3]);
            qfrag[kk] = __builtin_bit_cast(bf16x8, u);
        }
    }

    f32x4 acc[8];
#pragma unroll
    for (int dt = 0; dt < 8; ++dt) acc[dt] = (f32x4){0.f, 0.f, 0.f, 0.f};
    float m_r[4], l_r[4];
#pragma unroll
    for (int r = 0; r < 4; ++r) { m_r[r] = NEG_INF; l_r[r] = 0.f; }

    for (int kt = kt0; kt < q0 + QT; kt += KTILE) {
        __syncthreads();   // previous iteration's LDS reads done

        // stage K (row-major) and V (transposed), fp32 -> bf16
        {
            const int cg = tid & 31;    // float4 column group (128 cols)
            const int rr = tid >> 5;    // 0..7
#pragma unroll
            for (int it = 0; it < 8; ++it) {
                int r = rr + it * 8;
                const float* kp = K + hb + (long)(kt + r) * DIM + cg * 4;
                const float* vp = V + hb + (long)(kt + r) * DIM + cg * 4;
                f32x4 kx = *(const f32x4*)kp;
                f32x4 vx = *(const f32x4*)vp;
                u16x4 kb;
                kb[0]=f2bf(kx[0]); kb[1]=f2bf(kx[1]);
                kb[2]=f2bf(kx[2]); kb[3]=f2bf(kx[3]);
                *(u16x4*)&Kb[r * KSTR + cg * 4] = kb;
                Vt[(cg*4+0)*VSTR + r] = f2bf(vx[0]);
                Vt[(cg*4+1)*VSTR + r] = f2bf(vx[1]);
                Vt[(cg*4+2)*VSTR + r] = f2bf(vx[2]);
                Vt[(cg*4+3)*VSTR + r] = f2bf(vx[3]);
            }
        }
        __syncthreads();

        // S = Q K^T : 4 key n-tiles x 4 k-steps
        f32x4 sacc[4];
#pragma unroll
        for (int nt = 0; nt < 4; ++nt) sacc[nt] = (f32x4){0.f, 0.f, 0.f, 0.f};
#pragma unroll
        for (int kk = 0; kk < 4; ++kk) {
#pragma unroll
            for (int nt = 0; nt < 4; ++nt) {
                u16x8 bu = *(const u16x8*)&Kb[(nt*16 + l16) * KSTR + kk*32 + quad*8];
                sacc[nt] = __builtin_amdgcn_mfma_f32_16x16x32_bf16(
                    qfrag[kk], __builtin_bit_cast(bf16x8, bu), sacc[nt], 0, 0, 0);
            }
        }

        // mask + online softmax (C layout: row = quad*4+r, col = nt*16+l16)
        float sv[4][4];
#pragma unroll
        for (int nt = 0; nt < 4; ++nt) {
            int kj = kt + nt * 16 + l16;
#pragma unroll
            for (int r = 0; r < 4; ++r) {
                bool ok = (kj >= qstart[r]) && (kj <= qrow[r]);
                sv[nt][r] = ok ? sacc[nt][r] * scale : NEG_INF;
            }
        }
        float mnew[4], alpha[4], rsum[4];
#pragma unroll
        for (int r = 0; r < 4; ++r) {
            float tm = fmaxf(fmaxf(sv[0][r], sv[1][r]), fmaxf(sv[2][r], sv[3][r]));
#pragma unroll
            for (int off = 1; off < 16; off <<= 1)
                tm = fmaxf(tm, __shfl_xor(tm, off, 64));
            float mn = fmaxf(m_r[r], tm);
            mnew[r]  = mn;
            alpha[r] = (mn == NEG_INF) ? 1.f : __expf(m_r[r] - mn);
            rsum[r]  = 0.f;
        }
        float p[4][4];
#pragma unroll
        for (int nt = 0; nt < 4; ++nt)
#pragma unroll
            for (int r = 0; r < 4; ++r) {
                float pv = (sv[nt][r] == NEG_INF) ? 0.f : __expf(sv[nt][r] - mnew[r]);
                p[nt][r] = pv;
                rsum[r] += pv;
            }
#pragma unroll
        for (int r = 0; r < 4; ++r) {
            float s = rsum[r];
#pragma unroll
            for (int off = 1; off < 16; off <<= 1) s += __shfl_xor(s, off, 64);
            l_r[r] = l_r[r] * alpha[r] + s;
            m_r[r] = mnew[r];
        }
#pragma unroll
        for (int dt = 0; dt < 8; ++dt)
#pragma unroll
            for (int r = 0; r < 4; ++r) acc[dt][r] *= alpha[r];

        // P -> LDS (bf16), C layout write, then read back in A layout
#pragma unroll
        for (int nt = 0; nt < 4; ++nt)
#pragma unroll
            for (int r = 0; r < 4; ++r)
                Pw[wave][(quad*4 + r) * PSTR + nt*16 + l16] = f2bf(p[nt][r]);
        __syncthreads();   // intra-wave LDS RAW fence (uniform across block)

        // O += P V : 2 k-steps x 8 d n-tiles
#pragma unroll
        for (int kk2 = 0; kk2 < 2; ++kk2) {
            u16x8 au = *(const u16x8*)&Pw[wave][l16 * PSTR + kk2*32 + quad*8];
            bf16x8 ap = __builtin_bit_cast(bf16x8, au);
#pragma unroll
            for (int dt = 0; dt < 8; ++dt) {
                u16x8 bu = *(const u16x8*)&Vt[(dt*16 + l16) * VSTR + kk2*32 + quad*8];
                acc[dt] = __builtin_amdgcn_mfma_f32_16x16x32_bf16(
                    ap, __builtin_bit_cast(bf16x8, bu), acc[dt], 0, 0, 0);
            }
        }
    }

    // epilogue: O / l, fp32 store
#pragma unroll
    for (int r = 0; r < 4; ++r) {
        float inv = 1.f / l_r[r];
        float* op = O + hb + (long)qrow[r] * DIM + l16;
#pragma unroll
        for (int dt = 0; dt < 8; ++dt)
            op[dt * 16] = acc[dt][r] * inv;
    }
}

extern "C" void kernel_launch(void* const* d_in, const int* in_sizes, int n_in,
                              void* d_out, int out_size, void* d_ws, size_t ws_size,
                              hipStream_t stream) {
    const float* q = (const float*)d_in[0];
    const float* k = (const float*)d_in[1];
    const float* v = (const float*)d_in[2];
    const void* cu = d_in[3];
    int n_cu = in_sizes[3];
    int S = in_sizes[0] / (HEADS * DIM);
    dim3 grid(S / QT, HEADS);
    fa_blockcausal<<<grid, dim3(256), 0, stream>>>(
        q, k, v, cu, n_cu, (float*)d_out, S);
}